// Round 2
// baseline (771.368 us; speedup 1.0000x reference)
//
#include <hip/hip_runtime.h>
#include <cmath>

#define NUM_S   64
#define IMG_H   256
#define IMG_W   256
#define HWSZ    (IMG_H*IMG_W)          // 65536
#define BATCH   2
#define NPIX    (BATCH*HWSZ)           // 131072
#define NEL     (BATCH*NUM_S*HWSZ)     // 8388608
#define NSLICE  (BATCH*NUM_S)          // 128
#define VALID   246
#define INV_T   2.0f                   // 1/TEMP, TEMP=0.5
#define EPS_F   1e-20f
#define C1_F    1e-4f
#define C2_F    9e-4f

struct GK { float g[11]; };

// block-wide sum of a float, one double atomicAdd per block
__device__ inline void block_atomic_add(float v, double* dst) {
    __shared__ float sm[8];
    __syncthreads();                       // protect sm across repeated calls
    #pragma unroll
    for (int off = 32; off; off >>= 1) v += __shfl_down(v, off, 64);
    int lane = threadIdx.x & 63, w = threadIdx.x >> 6;
    if (lane == 0) sm[w] = v;
    __syncthreads();
    if (threadIdx.x == 0) {
        double s = 0.0;
        int nw = blockDim.x >> 6;
        for (int i = 0; i < nw; ++i) s += (double)sm[i];
        atomicAdd(dst, s);
    }
}

// Kernel 1: per-pixel online-softmax scan over slices (fwd + bwd thread
// halves). Stores {p, running_cummax} interleaved as float2 (8B stores,
// and gives the SSIM kernel 8B-coalesced paired loads). Fuses L1 sums.
__global__ __launch_bounds__(256) void scan_kernel(
    const float* __restrict__ img, const float* __restrict__ tgt,
    const float* __restrict__ un,
    float2* __restrict__ pt1, float2* __restrict__ pt2,
    double* __restrict__ acc)
{
    int tid = blockIdx.x * 256 + threadIdx.x;
    bool bwd = tid >= NPIX;                 // whole block is one direction
    int pix = bwd ? tid - NPIX : tid;
    int b  = pix >> 16;
    int hw = pix & (HWSZ - 1);
    int base = b * (NUM_S * HWSZ) + hw;
    int idx  = base + (bwd ? (NUM_S - 1) * HWSZ : 0);
    int step = bwd ? -HWSZ : HWSZ;
    float2* __restrict__ out = bwd ? pt2 : pt1;

    float m = -INFINITY, num = 0.f, den = 0.f, tmax = -INFINITY;
    float l1x = 0.f, l1p = 0.f;
    float x = img[idx], u = un[idx], t = tgt[idx];
    #pragma unroll 4
    for (int i = 0; i < NUM_S; ++i) {
        int nidx = idx + step;
        float nx = 0.f, nu = 0.f, nt = 0.f;
        if (i < NUM_S - 1) {                 // prefetch next triple (MLP)
            nx = img[nidx]; nu = un[nidx]; nt = tgt[nidx];
        }
        float gmb = -__logf(-__logf(u + EPS_F) + EPS_F);
        float yv = x + gmb;
        float mn = fmaxf(m, yv);             // online softmax
        float sc = __expf((m - mn) * INV_T); // m=-inf first iter -> 0
        float e  = __expf((yv - mn) * INV_T);
        num = num * sc + e * x;
        den = den * sc + e;
        m = mn;
        float p = num / den;
        tmax = fmaxf(tmax, t);
        out[idx] = make_float2(p, tmax);     // natural index: order irrelevant
        if (!bwd) l1x += fabsf(x - t);       // for L1/SSIM downstream
        l1p += fabsf(p - tmax);
        idx = nidx; x = nx; u = nu; t = nt;
    }
    block_atomic_add(l1x, &acc[0]);
    block_atomic_add(l1p, bwd ? &acc[2] : &acc[1]);
}

// Kernel 2: fused separable-Gaussian SSIM for one pair (blockIdx.z).
// 16x32 output tile -> v-LDS = 5*16*44*4 = 14.1 KB (~10 blocks/CU).
// Vertical blur direct-from-global (L2-resident) into swizzled LDS;
// horizontal blur via aligned ds_read_b128. Swizzle: float4 group g at row r
// stored at group (g+3r)%11 -- kills the r<->r+8 bank aliasing of stride 44.
__global__ __launch_bounds__(128) void ssim_kernel(
    const float* __restrict__ img, const float* __restrict__ tgt,
    const float2* __restrict__ pt1, const float2* __restrict__ pt2,
    GK gk, double* __restrict__ acc)
{
    __shared__ float v[5][16 * 44];
    int pair = blockIdx.z;
    int base = blockIdx.y * HWSZ;         // slice base
    int ty = blockIdx.x >> 3, tx = blockIdx.x & 7;
    int r0 = ty * 16, c0 = tx * 32;       // output-tile origin
    int rmax = min(16, VALID - r0);
    int cmax = min(32, VALID - c0);

    // ---- vertical blur: 42 cols x 2 row-groups(8 rows) = 84 tasks ----
    int task = threadIdx.x;
    if (task < 84) {
        int c  = task % 42;
        int rb = (task / 42) * 8;
        int gc = min(c0 + c, IMG_W - 1);  // clamp only feeds unused outputs
        float ax[18], ay[18];
        if (pair == 0) {
            #pragma unroll
            for (int k = 0; k < 18; ++k) {
                int gr = min(r0 + rb + k, IMG_H - 1);
                int idx = base + gr * IMG_W + gc;
                ax[k] = img[idx]; ay[k] = tgt[idx];
            }
        } else {
            const float2* __restrict__ pt = (pair == 1) ? pt1 : pt2;
            #pragma unroll
            for (int k = 0; k < 18; ++k) {
                int gr = min(r0 + rb + k, IMG_H - 1);
                float2 w = pt[base + gr * IMG_W + gc];
                ax[k] = w.x; ay[k] = w.y;
            }
        }
        int cg = c >> 2, cm = c & 3;
        #pragma unroll
        for (int j = 0; j < 8; ++j) {
            float sx = 0, sy = 0, sxx = 0, syy = 0, sxy = 0;
            #pragma unroll
            for (int k = 0; k < 11; ++k) {
                float w  = gk.g[k];
                float xv = ax[j + k], yv = ay[j + k];
                sx  += w * xv;      sy  += w * yv;
                sxx += w * xv * xv; syy += w * yv * yv;
                sxy += w * xv * yv;
            }
            int row = rb + j;
            int pg  = (cg + 3 * row) % 11;          // group swizzle
            int ad  = row * 44 + pg * 4 + cm;
            v[0][ad] = sx;  v[1][ad] = sy;
            v[2][ad] = sxx; v[3][ad] = syy; v[4][ad] = sxy;
        }
    }
    __syncthreads();

    // ---- horizontal blur + SSIM: 16 rows x 8 col-groups(4 cols) = 128 ----
    float lsum = 0.f;
    {
        int r   = threadIdx.x >> 3;
        int cbg = threadIdx.x & 7;
        int cb  = cbg * 4;
        if (r < rmax) {
            float t[5][16];
            #pragma unroll
            for (int j4 = 0; j4 < 4; ++j4) {
                int pg = (cbg + j4 + 3 * r) % 11;   // de-swizzle
                int ad = r * 44 + pg * 4;
                #pragma unroll
                for (int f = 0; f < 5; ++f) {
                    float4 q = *(const float4*)&v[f][ad];
                    t[f][j4*4+0] = q.x; t[f][j4*4+1] = q.y;
                    t[f][j4*4+2] = q.z; t[f][j4*4+3] = q.w;
                }
            }
            #pragma unroll
            for (int j = 0; j < 4; ++j) {
                if (cb + j < cmax) {
                    float o[5];
                    #pragma unroll
                    for (int f = 0; f < 5; ++f) {
                        float a = 0;
                        #pragma unroll
                        for (int k = 0; k < 11; ++k) a += gk.g[k] * t[f][j + k];
                        o[f] = a;
                    }
                    float m1 = o[0], m2 = o[1];
                    float s11 = o[2] - m1 * m1;
                    float s22 = o[3] - m2 * m2;
                    float s12 = o[4] - m1 * m2;
                    float nv = (2.f * m1 * m2 + C1_F) * (2.f * s12 + C2_F);
                    float dv = (m1 * m1 + m2 * m2 + C1_F) * (s11 + s22 + C2_F);
                    lsum += nv / dv;
                }
            }
        }
    }
    block_atomic_add(lsum, &acc[3 + pair]);
}

__global__ void finalize_kernel(const double* __restrict__ acc,
                                float* __restrict__ out) {
    double l1 = (acc[0] + acc[1] + acc[2]) / (double)NEL;
    double ss = (acc[3] + acc[4] + acc[5]) /
                ((double)NSLICE * (double)VALID * (double)VALID);
    out[0] = (float)(3.0 + l1 - ss);
}

extern "C" void kernel_launch(void* const* d_in, const int* in_sizes, int n_in,
                              void* d_out, int out_size, void* d_ws, size_t ws_size,
                              hipStream_t stream) {
    const float* img = (const float*)d_in[0];
    const float* tgt = (const float*)d_in[1];
    const float* un  = (const float*)d_in[2];
    float* out = (float*)d_out;

    // workspace: pt1, pt2 (float2[NEL] each, 64MB each) + 6 double accums
    float2* pt1 = (float2*)d_ws;
    float2* pt2 = pt1 + NEL;
    double* acc = (double*)(pt2 + NEL);

    hipMemsetAsync(acc, 0, 6 * sizeof(double), stream);

    GK gk;  // gaussian(11, sigma=1.5) computed in double, matches reference
    {
        double c[11], s = 0.0;
        for (int i = 0; i < 11; ++i) { double d = i - 5; c[i] = exp(-d * d / 4.5); s += c[i]; }
        for (int i = 0; i < 11; ++i) gk.g[i] = (float)(c[i] / s);
    }

    scan_kernel<<<(2 * NPIX) / 256, 256, 0, stream>>>(img, tgt, un, pt1, pt2, acc);
    ssim_kernel<<<dim3(128, NSLICE, 3), 128, 0, stream>>>(img, tgt, pt1, pt2, gk, acc);
    finalize_kernel<<<1, 1, 0, stream>>>(acc, out);
}

// Round 3
// 481.308 us; speedup vs baseline: 1.6027x; 1.6027x over previous
//
#include <hip/hip_runtime.h>
#include <cmath>

#define NUM_S   64
#define IMG_H   256
#define IMG_W   256
#define HWSZ    (IMG_H*IMG_W)          // 65536
#define BATCH   2
#define NPIX    (BATCH*HWSZ)           // 131072
#define NEL     (BATCH*NUM_S*HWSZ)     // 8388608
#define NSLICE  (BATCH*NUM_S)          // 128
#define VALID   246
#define INV_T   2.0f                   // 1/TEMP, TEMP=0.5
#define EPS_F   1e-20f
#define C1_F    1e-4f
#define C2_F    9e-4f

struct GK { float g[11]; };

// block-wide sum of a float, one double atomicAdd per block
__device__ inline void block_atomic_add(float v, double* dst) {
    __shared__ float sm[8];
    __syncthreads();                       // protect sm across repeated calls
    #pragma unroll
    for (int off = 32; off; off >>= 1) v += __shfl_down(v, off, 64);
    int lane = threadIdx.x & 63, w = threadIdx.x >> 6;
    if (lane == 0) sm[w] = v;
    __syncthreads();
    if (threadIdx.x == 0) {
        double s = 0.0;
        int nw = blockDim.x >> 6;
        for (int i = 0; i < nw; ++i) s += (double)sm[i];
        atomicAdd(dst, s);
    }
}

// Kernel 1: per-pixel online-softmax scan over slices (fwd + bwd thread
// halves). Double-buffered batch-8 loads: ~24 loads in flight per thread
// (R1/R2 were MLP-starved at ~1.4 TB/s). Stores {p, cummax} as float2.
__global__ __launch_bounds__(256) void scan_kernel(
    const float* __restrict__ img, const float* __restrict__ tgt,
    const float* __restrict__ un,
    float2* __restrict__ pt1, float2* __restrict__ pt2,
    double* __restrict__ acc)
{
    int tid = blockIdx.x * 256 + threadIdx.x;
    bool bwd = tid >= NPIX;                 // uniform per block (512 fwd blocks)
    int pix = bwd ? tid - NPIX : tid;
    int b  = pix >> 16;
    int hw = pix & (HWSZ - 1);
    int base = b * (NUM_S * HWSZ) + hw;
    int idx  = base + (bwd ? (NUM_S - 1) * HWSZ : 0);
    int step = bwd ? -HWSZ : HWSZ;
    float2* __restrict__ out = bwd ? pt2 : pt1;

    float m = -INFINITY, num = 0.f, den = 0.f, tmax = -INFINITY;
    float l1x = 0.f, l1p = 0.f;

    float xa[8], ua[8], ta[8], xb[8], ub[8], tb[8];
    #pragma unroll
    for (int j = 0; j < 8; ++j) {           // batch 0
        int id = idx + j * step;
        xa[j] = img[id]; ua[j] = un[id]; ta[j] = tgt[id];
    }

    auto doblock = [&](float (&xc)[8], float (&uc)[8], float (&tc)[8],
                       float (&xn)[8], float (&un_)[8], float (&tn)[8],
                       bool pref) {
        if (pref) {                          // prefetch next batch first
            #pragma unroll
            for (int j = 0; j < 8; ++j) {
                int id = idx + (8 + j) * step;
                xn[j] = img[id]; un_[j] = un[id]; tn[j] = tgt[id];
            }
        }
        #pragma unroll
        for (int j = 0; j < 8; ++j) {
            float x = xc[j], u = uc[j], t = tc[j];
            float gmb = -__logf(-__logf(u + EPS_F) + EPS_F);
            float yv = x + gmb;
            float mn = fmaxf(m, yv);             // online softmax
            float sc = __expf((m - mn) * INV_T); // m=-inf first iter -> 0
            float e  = __expf((yv - mn) * INV_T);
            num = num * sc + e * x;
            den = den * sc + e;
            m = mn;
            float p = num / den;
            tmax = fmaxf(tmax, t);
            out[idx + j * step] = make_float2(p, tmax);
            if (!bwd) l1x += fabsf(x - t);
            l1p += fabsf(p - tmax);
        }
        idx += 8 * step;
    };

    for (int q = 0; q < 4; ++q) {           // 8 batches of 8 slices
        doblock(xa, ua, ta, xb, ub, tb, true);
        doblock(xb, ub, tb, xa, ua, ta, q < 3);
    }
    block_atomic_add(l1x, &acc[0]);
    block_atomic_add(l1p, bwd ? &acc[2] : &acc[1]);
}

// Kernel 2: fused separable-Gaussian SSIM for one pair (blockIdx.z).
// 32x32 output tile, 256 threads, LDS 5*32*44*4 = 27.5 KB (5 blocks/CU).
// Vertical blur direct-from-global (L2-resident) into swizzled LDS;
// horizontal blur per-field (small register arrays -- no spill) via aligned
// ds_read_b128. Swizzle: float4 group g at row r stored at (g+3r)%11.
__global__ __launch_bounds__(256) void ssim_kernel(
    const float* __restrict__ img, const float* __restrict__ tgt,
    const float2* __restrict__ pt1, const float2* __restrict__ pt2,
    GK gk, double* __restrict__ acc)
{
    __shared__ float v[5][32 * 44];
    int pair = blockIdx.z;
    int base = blockIdx.y * HWSZ;         // slice base
    int ty = blockIdx.x >> 3, tx = blockIdx.x & 7;
    int r0 = ty * 32, c0 = tx * 32;       // output-tile origin
    int rmax = min(32, VALID - r0);
    int cmax = min(32, VALID - c0);

    // ---- vertical blur: 42 cols x 4 row-groups(8 rows) = 168 tasks ----
    int task = threadIdx.x;
    if (task < 168) {
        int c  = task % 42;
        int rb = (task / 42) * 8;
        int gc = min(c0 + c, IMG_W - 1);  // clamp only feeds unused outputs
        float ax[18], ay[18];
        if (pair == 0) {
            #pragma unroll
            for (int k = 0; k < 18; ++k) {
                int gr = min(r0 + rb + k, IMG_H - 1);
                int idx = base + gr * IMG_W + gc;
                ax[k] = img[idx]; ay[k] = tgt[idx];
            }
        } else {
            const float2* __restrict__ pt = (pair == 1) ? pt1 : pt2;
            #pragma unroll
            for (int k = 0; k < 18; ++k) {
                int gr = min(r0 + rb + k, IMG_H - 1);
                float2 w = pt[base + gr * IMG_W + gc];
                ax[k] = w.x; ay[k] = w.y;
            }
        }
        int cg = c >> 2, cm = c & 3;
        #pragma unroll
        for (int j = 0; j < 8; ++j) {
            float sx = 0, sy = 0, sxx = 0, syy = 0, sxy = 0;
            #pragma unroll
            for (int k = 0; k < 11; ++k) {
                float w  = gk.g[k];
                float xv = ax[j + k], yv = ay[j + k];
                sx  += w * xv;      sy  += w * yv;
                sxx += w * xv * xv; syy += w * yv * yv;
                sxy += w * xv * yv;
            }
            int row = rb + j;
            int pg  = (cg + 3 * row) % 11;          // group swizzle
            int ad  = row * 44 + pg * 4 + cm;
            v[0][ad] = sx;  v[1][ad] = sy;
            v[2][ad] = sxx; v[3][ad] = syy; v[4][ad] = sxy;
        }
    }
    __syncthreads();

    // ---- horizontal blur + SSIM: 32 rows x 8 col-groups(4 cols) = 256 ----
    float lsum = 0.f;
    {
        int r   = threadIdx.x >> 3;        // 0..31
        int cbg = threadIdx.x & 7;         // 0..7
        int cb  = cbg * 4;
        if (r < rmax) {
            float o[5][4];
            #pragma unroll
            for (int f = 0; f < 5; ++f) {   // per-field: only t[16] live
                float t[16];
                #pragma unroll
                for (int g4 = 0; g4 < 4; ++g4) {
                    int pg = (cbg + g4 + 3 * r) % 11;   // de-swizzle
                    float4 q = *(const float4*)&v[f][r * 44 + pg * 4];
                    t[g4*4+0] = q.x; t[g4*4+1] = q.y;
                    t[g4*4+2] = q.z; t[g4*4+3] = q.w;
                }
                #pragma unroll
                for (int j = 0; j < 4; ++j) {
                    float a = 0;
                    #pragma unroll
                    for (int k = 0; k < 11; ++k) a += gk.g[k] * t[j + k];
                    o[f][j] = a;
                }
            }
            #pragma unroll
            for (int j = 0; j < 4; ++j) {
                if (cb + j < cmax) {
                    float m1 = o[0][j], m2 = o[1][j];
                    float s11 = o[2][j] - m1 * m1;
                    float s22 = o[3][j] - m2 * m2;
                    float s12 = o[4][j] - m1 * m2;
                    float nv = (2.f * m1 * m2 + C1_F) * (2.f * s12 + C2_F);
                    float dv = (m1 * m1 + m2 * m2 + C1_F) * (s11 + s22 + C2_F);
                    lsum += nv / dv;
                }
            }
        }
    }
    block_atomic_add(lsum, &acc[3 + pair]);
}

__global__ void finalize_kernel(const double* __restrict__ acc,
                                float* __restrict__ out) {
    double l1 = (acc[0] + acc[1] + acc[2]) / (double)NEL;
    double ss = (acc[3] + acc[4] + acc[5]) /
                ((double)NSLICE * (double)VALID * (double)VALID);
    out[0] = (float)(3.0 + l1 - ss);
}

extern "C" void kernel_launch(void* const* d_in, const int* in_sizes, int n_in,
                              void* d_out, int out_size, void* d_ws, size_t ws_size,
                              hipStream_t stream) {
    const float* img = (const float*)d_in[0];
    const float* tgt = (const float*)d_in[1];
    const float* un  = (const float*)d_in[2];
    float* out = (float*)d_out;

    // workspace: pt1, pt2 (float2[NEL] each, 64MB each) + 6 double accums
    float2* pt1 = (float2*)d_ws;
    float2* pt2 = pt1 + NEL;
    double* acc = (double*)(pt2 + NEL);

    hipMemsetAsync(acc, 0, 6 * sizeof(double), stream);

    GK gk;  // gaussian(11, sigma=1.5) computed in double, matches reference
    {
        double c[11], s = 0.0;
        for (int i = 0; i < 11; ++i) { double d = i - 5; c[i] = exp(-d * d / 4.5); s += c[i]; }
        for (int i = 0; i < 11; ++i) gk.g[i] = (float)(c[i] / s);
    }

    scan_kernel<<<(2 * NPIX) / 256, 256, 0, stream>>>(img, tgt, un, pt1, pt2, acc);
    ssim_kernel<<<dim3(64, NSLICE, 3), 256, 0, stream>>>(img, tgt, pt1, pt2, gk, acc);
    finalize_kernel<<<1, 1, 0, stream>>>(acc, out);
}